// Round 13
// baseline (129.015 us; speedup 1.0000x reference)
//
#include <hip/hip_runtime.h>
#include <hip/hip_bf16.h>

#define NBOX  380
#define NLOCS 85
#define NINST 340   // B(4) * NLOCS(85)
#define SMB   7744  // per-batch LDS stride (floats)

// box index -> location index (from _recon_indices structure)
__device__ __forceinline__ int loc_of_box(int n) {
    if (n < 256) return n >> 2;               // fm=8, 4 boxes/loc
    if (n < 352) return 64 + (n - 256) / 6;   // fm=4, 6 boxes/loc
    if (n < 376) return 80 + (n - 352) / 6;   // fm=2, 6 boxes/loc
    return 84;                                // fm=1, 4 boxes/loc
}

__device__ __forceinline__ float f4e(const float4& v, int kk) {
    return (kk == 0) ? v.x : (kk == 1) ? v.y : (kk == 2) ? v.z : v.w;
}

// Per-batch softmax over depths + per-box affine params + rect + compaction.
__device__ void box_params_dev(int b, const float* __restrict__ zwhere,
    const int* __restrict__ zpresent, const float* __restrict__ zdepth,
    float* wgt, float* sxs, float* oxs, float* sys, float* oys,
    int* binst, int* rect, int* cidx, int* cnt, float* sm)
{
    float* sd  = sm;         // 384 (380 used)
    float* red = sm + 384;   // 512
    const int tid = threadIdx.x;

    if (tid < NBOX) {
        int loc = loc_of_box(tid);
        sd[tid] = (zpresent[b * NBOX + tid] == 1) ? zdepth[b * NLOCS + loc] : -1000.0f;
    }
    __syncthreads();

    float m = (tid < NBOX) ? sd[tid] : -1e30f;
    red[tid] = m; __syncthreads();
    for (int s = 256; s > 0; s >>= 1) {
        if (tid < s) red[tid] = fmaxf(red[tid], red[tid + s]);
        __syncthreads();
    }
    m = red[0]; __syncthreads();

    float sum = (tid < NBOX) ? expf(sd[tid] - m) : 0.f;
    red[tid] = sum; __syncthreads();
    for (int s = 256; s > 0; s >>= 1) {
        if (tid < s) red[tid] += red[tid + s];
        __syncthreads();
    }
    float inv = 1.0f / red[0];
    __syncthreads();

    if (tid < NBOX) {
        int g = b * NBOX + tid;
        float wv = expf(sd[tid] - m) * inv;   // exp(-1000-m) underflows to exactly 0
        wgt[g] = wv;
        float cx = zwhere[g * 4 + 0], cy = zwhere[g * 4 + 1];
        float w  = zwhere[g * 4 + 2], h  = zwhere[g * 4 + 3];
        float isx = 1.0f / fmaxf(w, 1e-5f);
        float isy = 1.0f / fmaxf(h, 1e-5f);
        float sxv = isx * (63.0f / 127.0f);
        float oxv = 31.5f * (1.0f - 2.0f * cx * isx);
        float syv = isy * (63.0f / 127.0f);
        float oyv = 31.5f * (1.0f - 2.0f * cy * isy);
        sxs[g] = sxv; oxs[g] = oxv; sys[g] = syv; oys[g] = oyv;
        binst[g] = b * NLOCS + loc_of_box(tid);
        int wlo = min(127, max(0, (int)floorf((-1.0f - oxv) / sxv)));
        int whi = max(0, min(127, (int)ceilf((64.0f - oxv) / sxv)));
        int hlo = min(127, max(0, (int)floorf((-1.0f - oyv) / syv)));
        int hhi = max(0, min(127, (int)ceilf((64.0f - oyv) / syv)));
        rect[g] = wlo | (whi << 8) | (hlo << 16) | (hhi << 24);
        sd[tid] = wv;   // presence flag for compaction
    }
    __syncthreads();

    if (tid < 64) {   // wave 0: deterministic ascending compaction
        int base = 0;
        for (int c = 0; c < 6; ++c) {
            int n = c * 64 + tid;
            bool p = (n < NBOX) && (sd[n] > 0.0f);
            unsigned long long mask = __ballot(p);
            int pos = __popcll(mask & ((1ull << tid) - 1ull));
            if (p) cidx[b * NBOX + base + pos] = n;
            base += __popcll(mask);
        }
        if (tid == 0) cnt[b] = base;
    }
}

// Decoder: ONE (loc, batch-pair, row-half) per block, 512 threads.
// R12 diagnosis: all prior variants issued ~1 ds_read_b128 per 4 FMAs ->
// LDS-instruction pipe saturated (~46 us-CU per block). THIS version uses
// per-thread co-tiles of 4 via float4 weight loads: each x b128 feeds
// 4k x 4co x 2batch = 32 FMAs per 2 LDS reads (16:1) -> LDS instr ~3x down.
// out[(2i+di, 2j+dj)][co] = act( b[co] + sum_k x[i,j][k] * W[3-(2di+dj)][k][co] )
// Per-batch LDS (floats, +q*SMB): s_x 0 | aL0 64 | aL1 576 | aL2 1600 |
//   aL3 3648 (stride 32) | aL4 overlay 0 (128 px * stride 20, 16B-aligned).
// Rules: register arrays static-indexed only (R8); 2 blocks/CU by LDS.
__global__ __launch_bounds__(512, 2) void decode_fused_k(
    const float* __restrict__ z_what,
    const float* __restrict__ W0, const float* __restrict__ B0,
    const float* __restrict__ W1, const float* __restrict__ B1,
    const float* __restrict__ W2, const float* __restrict__ B2,
    const float* __restrict__ W3, const float* __restrict__ B3,
    const float* __restrict__ W4, const float* __restrict__ B4,
    const float* __restrict__ W5, const float* __restrict__ B5,
    const float* __restrict__ z_where, const int* __restrict__ z_present,
    const float* __restrict__ z_depth,
    float* __restrict__ wgt, float* __restrict__ sxs, float* __restrict__ oxs,
    float* __restrict__ sys, float* __restrict__ oys, int* __restrict__ binst,
    int* __restrict__ rect, int* __restrict__ cidx, int* __restrict__ cnt,
    float* __restrict__ dec)
{
    __shared__ __align__(16) float sm[2 * SMB];   // 61,952 B

    const int bid = blockIdx.x;
    if (bid >= NINST) {   // 4 trailing blocks: box params
        box_params_dev(bid - NINST, z_where, z_present, z_depth,
                       wgt, sxs, oxs, sys, oys, binst, rect, cidx, cnt, sm);
        return;
    }
    const int loc = bid % 85;
    const int r2g = bid / 85;                // 0..3
    const int bp = r2g & 1, s = r2g >> 1;    // batch-pair, row-half
    const int inst0 = (2 * bp + 0) * 85 + loc;
    const int inst1 = (2 * bp + 1) * 85 + loc;

    const int tid = threadIdx.x;

    if (tid < 128) {   // s_x for both batches
        int q = tid >> 6, l = tid & 63;
        sm[q * SMB + l] = z_what[(q ? inst1 : inst0) * 64 + l];
    }
    __syncthreads();

    // ---- L0: K=64 -> 256ch, row s, cols 0..1. thread=(j0, c0), 2 batches.
    {
        const int c0 = tid & 255, j0 = tid >> 8;
        const int ft = 3 - (2 * s + j0);
        const float* wp = W0 + (size_t)ft * 64 * 256 + c0;
        float aA = 0.f, aB = 0.f;
        #pragma unroll 4
        for (int kq = 0; kq < 16; ++kq) {
            float4 xA = *(const float4*)&sm[kq * 4];
            float4 xB = *(const float4*)&sm[SMB + kq * 4];
            #pragma unroll
            for (int kk = 0; kk < 4; ++kk) {
                float w = wp[(kq * 4 + kk) * 256];
                aA = fmaf(f4e(xA, kk), w, aA);
                aB = fmaf(f4e(xB, kk), w, aB);
            }
        }
        float bb = B0[c0];
        sm[64 + j0 * 256 + c0]       = fmaxf(aA + bb, 0.f);
        sm[SMB + 64 + j0 * 256 + c0] = fmaxf(aB + bb, 0.f);
    }
    __syncthreads();

    // ---- L1: K=256 -> 128ch, rows 2s..2s+1, cols 0..3. 256 threads:
    // thread=(tap, co4, j): co-tile 4, x b128 feeds 32 FMAs.
    if (tid < 256) {
        const int t = tid >> 6, co4 = (tid >> 1) & 31, j = tid & 1;
        const int di = t >> 1, dj = t & 1, ft = 3 - t;
        const float* wp = W1 + (size_t)ft * 256 * 128 + co4 * 4;
        float aA[4] = {0.f,0.f,0.f,0.f}, aB[4] = {0.f,0.f,0.f,0.f};
        #pragma unroll 4
        for (int kq = 0; kq < 64; ++kq) {
            float4 xA = *(const float4*)&sm[64 + j * 256 + kq * 4];
            float4 xB = *(const float4*)&sm[SMB + 64 + j * 256 + kq * 4];
            #pragma unroll
            for (int kk = 0; kk < 4; ++kk) {
                float4 w4 = *(const float4*)&wp[(kq * 4 + kk) * 128];
                float xa = f4e(xA, kk), xb = f4e(xB, kk);
                aA[0] = fmaf(xa, w4.x, aA[0]); aA[1] = fmaf(xa, w4.y, aA[1]);
                aA[2] = fmaf(xa, w4.z, aA[2]); aA[3] = fmaf(xa, w4.w, aA[3]);
                aB[0] = fmaf(xb, w4.x, aB[0]); aB[1] = fmaf(xb, w4.y, aB[1]);
                aB[2] = fmaf(xb, w4.z, aB[2]); aB[3] = fmaf(xb, w4.w, aB[3]);
            }
        }
        float4 b4 = *(const float4*)&B1[co4 * 4];
        int o = (di * 4 + 2 * j + dj) * 128 + co4 * 4;
        *(float4*)&sm[576 + o] = make_float4(
            fmaxf(aA[0] + b4.x, 0.f), fmaxf(aA[1] + b4.y, 0.f),
            fmaxf(aA[2] + b4.z, 0.f), fmaxf(aA[3] + b4.w, 0.f));
        *(float4*)&sm[SMB + 576 + o] = make_float4(
            fmaxf(aB[0] + b4.x, 0.f), fmaxf(aB[1] + b4.y, 0.f),
            fmaxf(aB[2] + b4.z, 0.f), fmaxf(aB[3] + b4.w, 0.f));
    }
    __syncthreads();

    // ---- L2: K=128 -> 64ch, out 4 rows x 8 cols. thread=(orow, ocol, co4).
    {
        const int orow = tid >> 7, ocol = (tid >> 4) & 7, co4 = tid & 15;
        const int i = orow >> 1, di = orow & 1, j = ocol >> 1, dj = ocol & 1;
        const int ft = 3 - (2 * di + dj);
        const float* wp = W2 + (size_t)ft * 128 * 64 + co4 * 4;
        float aA[4] = {0.f,0.f,0.f,0.f}, aB[4] = {0.f,0.f,0.f,0.f};
        #pragma unroll 4
        for (int kq = 0; kq < 32; ++kq) {
            float4 xA = *(const float4*)&sm[576 + (i * 4 + j) * 128 + kq * 4];
            float4 xB = *(const float4*)&sm[SMB + 576 + (i * 4 + j) * 128 + kq * 4];
            #pragma unroll
            for (int kk = 0; kk < 4; ++kk) {
                float4 w4 = *(const float4*)&wp[(kq * 4 + kk) * 64];
                float xa = f4e(xA, kk), xb = f4e(xB, kk);
                aA[0] = fmaf(xa, w4.x, aA[0]); aA[1] = fmaf(xa, w4.y, aA[1]);
                aA[2] = fmaf(xa, w4.z, aA[2]); aA[3] = fmaf(xa, w4.w, aA[3]);
                aB[0] = fmaf(xb, w4.x, aB[0]); aB[1] = fmaf(xb, w4.y, aB[1]);
                aB[2] = fmaf(xb, w4.z, aB[2]); aB[3] = fmaf(xb, w4.w, aB[3]);
            }
        }
        float4 b4 = *(const float4*)&B2[co4 * 4];
        int o = (orow * 8 + ocol) * 64 + co4 * 4;
        *(float4*)&sm[1600 + o] = make_float4(
            fmaxf(aA[0] + b4.x, 0.f), fmaxf(aA[1] + b4.y, 0.f),
            fmaxf(aA[2] + b4.z, 0.f), fmaxf(aA[3] + b4.w, 0.f));
        *(float4*)&sm[SMB + 1600 + o] = make_float4(
            fmaxf(aB[0] + b4.x, 0.f), fmaxf(aB[1] + b4.y, 0.f),
            fmaxf(aB[2] + b4.z, 0.f), fmaxf(aB[3] + b4.w, 0.f));
    }
    __syncthreads();

    // ---- L3: K=64 -> 32ch, out 8 rows x 16 cols. thread=(orow, ocol, co4),
    // px-pair (ocol, ocol+8) shares tap & weights.
    {
        const int orow = tid >> 6, ocol = (tid >> 3) & 7, co4 = tid & 7;
        const int i = orow >> 1, di = orow & 1, dj = ocol & 1;
        const int j1 = ocol >> 1, j2 = j1 + 4;
        const int ft = 3 - (2 * di + dj);
        const float* wp = W3 + (size_t)ft * 64 * 32 + co4 * 4;
        float a1A[4] = {0.f,0.f,0.f,0.f}, a1B[4] = {0.f,0.f,0.f,0.f};
        float a2A[4] = {0.f,0.f,0.f,0.f}, a2B[4] = {0.f,0.f,0.f,0.f};
        #pragma unroll 2
        for (int kq = 0; kq < 16; ++kq) {
            float4 x1A = *(const float4*)&sm[1600 + (i * 8 + j1) * 64 + kq * 4];
            float4 x2A = *(const float4*)&sm[1600 + (i * 8 + j2) * 64 + kq * 4];
            float4 x1B = *(const float4*)&sm[SMB + 1600 + (i * 8 + j1) * 64 + kq * 4];
            float4 x2B = *(const float4*)&sm[SMB + 1600 + (i * 8 + j2) * 64 + kq * 4];
            #pragma unroll
            for (int kk = 0; kk < 4; ++kk) {
                float4 w4 = *(const float4*)&wp[(kq * 4 + kk) * 32];
                float e1a = f4e(x1A, kk), e2a = f4e(x2A, kk);
                float e1b = f4e(x1B, kk), e2b = f4e(x2B, kk);
                a1A[0] = fmaf(e1a, w4.x, a1A[0]); a1A[1] = fmaf(e1a, w4.y, a1A[1]);
                a1A[2] = fmaf(e1a, w4.z, a1A[2]); a1A[3] = fmaf(e1a, w4.w, a1A[3]);
                a2A[0] = fmaf(e2a, w4.x, a2A[0]); a2A[1] = fmaf(e2a, w4.y, a2A[1]);
                a2A[2] = fmaf(e2a, w4.z, a2A[2]); a2A[3] = fmaf(e2a, w4.w, a2A[3]);
                a1B[0] = fmaf(e1b, w4.x, a1B[0]); a1B[1] = fmaf(e1b, w4.y, a1B[1]);
                a1B[2] = fmaf(e1b, w4.z, a1B[2]); a1B[3] = fmaf(e1b, w4.w, a1B[3]);
                a2B[0] = fmaf(e2b, w4.x, a2B[0]); a2B[1] = fmaf(e2b, w4.y, a2B[1]);
                a2B[2] = fmaf(e2b, w4.z, a2B[2]); a2B[3] = fmaf(e2b, w4.w, a2B[3]);
            }
        }
        float4 b4 = *(const float4*)&B3[co4 * 4];
        int o1 = (orow * 16 + ocol) * 32 + co4 * 4;
        int o2 = (orow * 16 + ocol + 8) * 32 + co4 * 4;
        *(float4*)&sm[3648 + o1] = make_float4(
            fmaxf(a1A[0] + b4.x, 0.f), fmaxf(a1A[1] + b4.y, 0.f),
            fmaxf(a1A[2] + b4.z, 0.f), fmaxf(a1A[3] + b4.w, 0.f));
        *(float4*)&sm[3648 + o2] = make_float4(
            fmaxf(a2A[0] + b4.x, 0.f), fmaxf(a2A[1] + b4.y, 0.f),
            fmaxf(a2A[2] + b4.z, 0.f), fmaxf(a2A[3] + b4.w, 0.f));
        *(float4*)&sm[SMB + 3648 + o1] = make_float4(
            fmaxf(a1B[0] + b4.x, 0.f), fmaxf(a1B[1] + b4.y, 0.f),
            fmaxf(a1B[2] + b4.z, 0.f), fmaxf(a1B[3] + b4.w, 0.f));
        *(float4*)&sm[SMB + 3648 + o2] = make_float4(
            fmaxf(a2B[0] + b4.x, 0.f), fmaxf(a2B[1] + b4.y, 0.f),
            fmaxf(a2B[2] + b4.z, 0.f), fmaxf(a2B[3] + b4.w, 0.f));
    }
    __syncthreads();

    // ---- L4 + L5 fused, 4 chunks (2 L3 rows -> 4 L4 rows -> 8 final rows).
    const int x5 = tid & 63, g5 = tid >> 6;
    const int dj5 = x5 & 1, di5 = g5 & 1;
    const int ft5 = 3 - (2 * di5 + dj5);
    float w5r[16][3];
    #pragma unroll
    for (int k = 0; k < 16; ++k) {
        w5r[k][0] = W5[(ft5 * 16 + k) * 3 + 0];
        w5r[k][1] = W5[(ft5 * 16 + k) * 3 + 1];
        w5r[k][2] = W5[(ft5 * 16 + k) * 3 + 2];
    }
    const float b50 = B5[0], b51 = B5[1], b52 = B5[2];

    for (int c = 0; c < 4; ++c) {
        {   // L4: K=32 -> 16ch; chunk out rows 0..3 local, 32 cols.
            const int ocol = tid >> 4, orow = (tid >> 2) & 3, co4 = tid & 3;
            const int il3 = 2 * c + (orow >> 1), di = orow & 1;
            const int j = ocol >> 1, dj = ocol & 1;
            const int ft = 3 - (2 * di + dj);
            const float* wp = W4 + (size_t)ft * 32 * 16 + co4 * 4;
            float aA[4] = {0.f,0.f,0.f,0.f}, aB[4] = {0.f,0.f,0.f,0.f};
            #pragma unroll
            for (int kq = 0; kq < 8; ++kq) {
                float4 xA = *(const float4*)&sm[3648 + (il3 * 16 + j) * 32 + kq * 4];
                float4 xB = *(const float4*)&sm[SMB + 3648 + (il3 * 16 + j) * 32 + kq * 4];
                #pragma unroll
                for (int kk = 0; kk < 4; ++kk) {
                    float4 w4 = *(const float4*)&wp[(kq * 4 + kk) * 16];
                    float xa = f4e(xA, kk), xb = f4e(xB, kk);
                    aA[0] = fmaf(xa, w4.x, aA[0]); aA[1] = fmaf(xa, w4.y, aA[1]);
                    aA[2] = fmaf(xa, w4.z, aA[2]); aA[3] = fmaf(xa, w4.w, aA[3]);
                    aB[0] = fmaf(xb, w4.x, aB[0]); aB[1] = fmaf(xb, w4.y, aB[1]);
                    aB[2] = fmaf(xb, w4.z, aB[2]); aB[3] = fmaf(xb, w4.w, aB[3]);
                }
            }
            float4 b4 = *(const float4*)&B4[co4 * 4];
            int o = (orow * 32 + ocol) * 20 + co4 * 4;   // stride 20 = 80B, 16B-aligned
            *(float4*)&sm[o] = make_float4(
                fmaxf(aA[0] + b4.x, 0.f), fmaxf(aA[1] + b4.y, 0.f),
                fmaxf(aA[2] + b4.z, 0.f), fmaxf(aA[3] + b4.w, 0.f));
            *(float4*)&sm[SMB + o] = make_float4(
                fmaxf(aB[0] + b4.x, 0.f), fmaxf(aB[1] + b4.y, 0.f),
                fmaxf(aB[2] + b4.z, 0.f), fmaxf(aB[3] + b4.w, 0.f));
        }
        __syncthreads();
        {   // L5: K=16 -> 3ch sigmoid; out rows 8c+g5 (global 32s+8c+g5), col x5.
            const int j = x5 >> 1, lr = g5 >> 1;
            const int base = (lr * 32 + j) * 20;
            float aA0 = b50, aA1 = b51, aA2 = b52;
            float aB0 = b50, aB1 = b51, aB2 = b52;
            #pragma unroll
            for (int kq = 0; kq < 4; ++kq) {
                float4 xA = *(const float4*)&sm[base + kq * 4];
                float4 xB = *(const float4*)&sm[SMB + base + kq * 4];
                #pragma unroll
                for (int kk = 0; kk < 4; ++kk) {
                    int k = kq * 4 + kk;
                    float xa = f4e(xA, kk), xb = f4e(xB, kk);
                    aA0 = fmaf(xa, w5r[k][0], aA0);
                    aA1 = fmaf(xa, w5r[k][1], aA1);
                    aA2 = fmaf(xa, w5r[k][2], aA2);
                    aB0 = fmaf(xb, w5r[k][0], aB0);
                    aB1 = fmaf(xb, w5r[k][1], aB1);
                    aB2 = fmaf(xb, w5r[k][2], aB2);
                }
            }
            int row = 32 * s + 8 * c + g5;
            float* dpA = dec + (size_t)inst0 * 12288 + (size_t)(row * 64 + x5) * 3;
            float* dpB = dec + (size_t)inst1 * 12288 + (size_t)(row * 64 + x5) * 3;
            dpA[0] = 1.0f / (1.0f + expf(-aA0));
            dpA[1] = 1.0f / (1.0f + expf(-aA1));
            dpA[2] = 1.0f / (1.0f + expf(-aA2));
            dpB[0] = 1.0f / (1.0f + expf(-aB0));
            dpB[1] = 1.0f / (1.0f + expf(-aB1));
            dpB[2] = 1.0f / (1.0f + expf(-aB2));
        }
        __syncthreads();
    }
}

// Fused STN bilinear sample + weighted composite + in-block reduce.
// grid 512 = (b, 16x8 px tile); 1024 threads = 8 box-splits x 128 px.
__global__ __launch_bounds__(1024) void composite_k(
    const float* __restrict__ dec, const float* __restrict__ wgt,
    const float* __restrict__ sxs, const float* __restrict__ oxs,
    const float* __restrict__ sys, const float* __restrict__ oys,
    const int* __restrict__ binst, const int* __restrict__ rect,
    const int* __restrict__ cidx, const int* __restrict__ cnt,
    float* __restrict__ out)
{
    __shared__ float pls[8][128][3];   // 12 KB

    int b = blockIdx.x >> 7, tile = blockIdx.x & 127;      // 8 x-tiles x 16 y-tiles
    int tx0 = (tile & 7) << 4, ty0 = (tile >> 3) << 3;     // 16 wide x 8 tall
    int s = threadIdx.x >> 7, px = threadIdx.x & 127;
    int lx = px & 15, ly = px >> 4;                        // 16 x 8
    int w = tx0 + lx, h = ty0 + ly;

    int nb = cnt[b];
    int lo = (nb * s) >> 3, hi = (nb * (s + 1)) >> 3;

    float fw = (float)w, fh = (float)h;
    float a0 = 0.f, a1 = 0.f, a2 = 0.f;
    for (int q = lo; q < hi; ++q) {
        int n = cidx[b * NBOX + q];
        int rc = rect[b * NBOX + n];
        int wlo = rc & 255, whi = (rc >> 8) & 255;
        int hlo = (rc >> 16) & 255, hhi = (rc >> 24) & 255;
        if (whi < tx0 || wlo > tx0 + 15 || hhi < ty0 || hlo > ty0 + 7) continue;
        int g = b * NBOX + n;
        float wg = wgt[g];
        float pxx = fmaf(fw, sxs[g], oxs[g]);
        float pyy = fmaf(fh, sys[g], oys[g]);
        float x0 = floorf(pxx), y0 = floorf(pyy);
        if (x0 < -1.0f || x0 > 63.0f || y0 < -1.0f || y0 > 63.0f) continue;
        float wx = pxx - x0, wy = pyy - y0;
        int ix = (int)x0, iy = (int)y0;
        int x0c = max(ix, 0), x1c = min(ix + 1, 63);
        int y0c = max(iy, 0), y1c = min(iy + 1, 63);
        float m00 = (ix >= 0 && iy >= 0) ? 1.f : 0.f;
        float m01 = (ix + 1 <= 63 && iy >= 0) ? 1.f : 0.f;
        float m10 = (ix >= 0 && iy + 1 <= 63) ? 1.f : 0.f;
        float m11 = (ix + 1 <= 63 && iy + 1 <= 63) ? 1.f : 0.f;
        float w00 = (1.f - wy) * (1.f - wx) * m00;
        float w01 = (1.f - wy) * wx * m01;
        float w10 = wy * (1.f - wx) * m10;
        float w11 = wy * wx * m11;
        const float* img = dec + (size_t)binst[g] * 12288;   // (64,64,3) HWC
        int b00 = (y0c * 64 + x0c) * 3, b01 = (y0c * 64 + x1c) * 3;
        int b10 = (y1c * 64 + x0c) * 3, b11 = (y1c * 64 + x1c) * 3;
        a0 += wg * (w00 * img[b00]   + w01 * img[b01]   + w10 * img[b10]   + w11 * img[b11]);
        a1 += wg * (w00 * img[b00+1] + w01 * img[b01+1] + w10 * img[b10+1] + w11 * img[b11+1]);
        a2 += wg * (w00 * img[b00+2] + w01 * img[b01+2] + w10 * img[b10+2] + w11 * img[b11+2]);
    }
    pls[s][px][0] = a0; pls[s][px][1] = a1; pls[s][px][2] = a2;
    __syncthreads();

    if (threadIdx.x < 384) {
        int c = threadIdx.x >> 7, p2 = threadIdx.x & 127;
        float v = 0.f;
        #pragma unroll
        for (int t = 0; t < 8; ++t) v += pls[t][p2][c];
        int h2 = ty0 + (p2 >> 4), w2 = tx0 + (p2 & 15);
        out[((b * 3 + c) * 128 + h2) * 128 + w2] = v;
    }
}

extern "C" void kernel_launch(void* const* d_in, const int* in_sizes, int n_in,
                              void* d_out, int out_size, void* d_ws, size_t ws_size,
                              hipStream_t stream)
{
    const float* z_what    = (const float*)d_in[0];   // (4,85,64)
    const float* z_where   = (const float*)d_in[1];   // (4,380,4)
    const int*   z_present = (const int*)  d_in[2];   // (4,380,1)
    const float* z_depth   = (const float*)d_in[3];   // (4,85,1)

    // workspace: dec 16.71 MB | params ~55 KB
    char* ws = (char*)d_ws;
    float* dec = (float*)ws;                           // 340*12288 f32
    float* P   = (float*)(ws + 16711680);
    float* wgt = P,        *sxs = P + 1520, *oxs = P + 2 * 1520;
    float* sys = P + 3 * 1520, *oys = P + 4 * 1520;
    int* binst = (int*)(P + 5 * 1520);
    int* rect  = binst + 1520;
    int* cidx  = binst + 2 * 1520;
    int* cnt   = binst + 3 * 1520;

    decode_fused_k<<<dim3(NINST + 4), dim3(512), 0, stream>>>(
        z_what,
        (const float*)d_in[4],  (const float*)d_in[5],
        (const float*)d_in[6],  (const float*)d_in[7],
        (const float*)d_in[8],  (const float*)d_in[9],
        (const float*)d_in[10], (const float*)d_in[11],
        (const float*)d_in[12], (const float*)d_in[13],
        (const float*)d_in[14], (const float*)d_in[15],
        z_where, z_present, z_depth,
        wgt, sxs, oxs, sys, oys, binst, rect, cidx, cnt,
        dec);

    composite_k<<<dim3(512), dim3(1024), 0, stream>>>(
        dec, wgt, sxs, oxs, sys, oys, binst, rect, cidx, cnt, (float*)d_out);
}

// Round 14
// 120.206 us; speedup vs baseline: 1.0733x; 1.0733x over previous
//
#include <hip/hip_runtime.h>
#include <hip/hip_bf16.h>

#define NBOX  380
#define NLOCS 85
#define NINST 340   // B(4) * NLOCS(85)
#define SMB   6368  // per-batch LDS stride (floats)
#define W5T   12736 // W5 transposed stage offset (floats)

// box index -> location index (from _recon_indices structure)
__device__ __forceinline__ int loc_of_box(int n) {
    if (n < 256) return n >> 2;               // fm=8, 4 boxes/loc
    if (n < 352) return 64 + (n - 256) / 6;   // fm=4, 6 boxes/loc
    if (n < 376) return 80 + (n - 352) / 6;   // fm=2, 6 boxes/loc
    return 84;                                // fm=1, 4 boxes/loc
}

__device__ __forceinline__ float f4e(const float4& v, int kk) {
    return (kk == 0) ? v.x : (kk == 1) ? v.y : (kk == 2) ? v.z : v.w;
}

// Per-batch softmax over depths + per-box affine params + rect + compaction.
__device__ void box_params_dev(int b, const float* __restrict__ zwhere,
    const int* __restrict__ zpresent, const float* __restrict__ zdepth,
    float* wgt, float* sxs, float* oxs, float* sys, float* oys,
    int* binst, int* rect, int* cidx, int* cnt, float* sm)
{
    float* sd  = sm;         // 384 (380 used)
    float* red = sm + 384;   // 512
    const int tid = threadIdx.x;

    if (tid < NBOX) {
        int loc = loc_of_box(tid);
        sd[tid] = (zpresent[b * NBOX + tid] == 1) ? zdepth[b * NLOCS + loc] : -1000.0f;
    }
    __syncthreads();

    float m = (tid < NBOX) ? sd[tid] : -1e30f;
    red[tid] = m; __syncthreads();
    for (int s = 256; s > 0; s >>= 1) {
        if (tid < s) red[tid] = fmaxf(red[tid], red[tid + s]);
        __syncthreads();
    }
    m = red[0]; __syncthreads();

    float sum = (tid < NBOX) ? expf(sd[tid] - m) : 0.f;
    red[tid] = sum; __syncthreads();
    for (int s = 256; s > 0; s >>= 1) {
        if (tid < s) red[tid] += red[tid + s];
        __syncthreads();
    }
    float inv = 1.0f / red[0];
    __syncthreads();

    if (tid < NBOX) {
        int g = b * NBOX + tid;
        float wv = expf(sd[tid] - m) * inv;   // exp(-1000-m) underflows to exactly 0
        wgt[g] = wv;
        float cx = zwhere[g * 4 + 0], cy = zwhere[g * 4 + 1];
        float w  = zwhere[g * 4 + 2], h  = zwhere[g * 4 + 3];
        float isx = 1.0f / fmaxf(w, 1e-5f);
        float isy = 1.0f / fmaxf(h, 1e-5f);
        float sxv = isx * (63.0f / 127.0f);
        float oxv = 31.5f * (1.0f - 2.0f * cx * isx);
        float syv = isy * (63.0f / 127.0f);
        float oyv = 31.5f * (1.0f - 2.0f * cy * isy);
        sxs[g] = sxv; oxs[g] = oxv; sys[g] = syv; oys[g] = oyv;
        binst[g] = b * NLOCS + loc_of_box(tid);
        int wlo = min(127, max(0, (int)floorf((-1.0f - oxv) / sxv)));
        int whi = max(0, min(127, (int)ceilf((64.0f - oxv) / sxv)));
        int hlo = min(127, max(0, (int)floorf((-1.0f - oyv) / syv)));
        int hhi = max(0, min(127, (int)ceilf((64.0f - oyv) / syv)));
        rect[g] = wlo | (whi << 8) | (hlo << 16) | (hhi << 24);
        sd[tid] = wv;   // presence flag for compaction
    }
    __syncthreads();

    if (tid < 64) {   // wave 0: deterministic ascending compaction
        int base = 0;
        for (int c = 0; c < 6; ++c) {
            int n = c * 64 + tid;
            bool p = (n < NBOX) && (sd[n] > 0.0f);
            unsigned long long mask = __ballot(p);
            int pos = __popcll(mask & ((1ull << tid) - 1ull));
            if (p) cidx[b * NBOX + base + pos] = n;
            base += __popcll(mask);
        }
        if (tid == 0) cnt[b] = base;
    }
}

// Decoder: ONE (loc, batch-pair, row-half) per block, 512 threads.
// Co-tile-4 weights (float4 loads): x b128 feeds 16-32 FMAs (LDS-pipe relief).
// R13 post-mortem fixes: (a) W5 staged TRANSPOSED in LDS, not 48 registers
// held across the chunk loop (that spilled: VGPR=128 cap, +24MB scratch);
// (b) all LDS strides padded !=0 mod 32 banks AND float4-aligned
// (aL1 132, aL2 68, aL3 36, aL4 20) -- R13's stride-32 aL3 was a bank-aligned
// conflict (2.28M); (c) L3 chunked (2 rows/chunk from aL2 row c) to shrink
// live LDS and register sets.
// out[(2i+di, 2j+dj)][co] = act( b[co] + sum_k x[i,j][k] * W[3-(2di+dj)][k][co] )
// Per-batch LDS (floats, +q*SMB): s_x 0 | aL0 64 | aL1 576 (stride 132) |
//   aL2 1632 (stride 68) | aL3c overlay 0 (32px * 36) | aL4 3808 (128px * 20).
// W5t shared at 12736 (192). Total 12928 floats = 51,712 B -> 2+ blocks/CU.
__global__ __launch_bounds__(512, 2) void decode_fused_k(
    const float* __restrict__ z_what,
    const float* __restrict__ W0, const float* __restrict__ B0,
    const float* __restrict__ W1, const float* __restrict__ B1,
    const float* __restrict__ W2, const float* __restrict__ B2,
    const float* __restrict__ W3, const float* __restrict__ B3,
    const float* __restrict__ W4, const float* __restrict__ B4,
    const float* __restrict__ W5, const float* __restrict__ B5,
    const float* __restrict__ z_where, const int* __restrict__ z_present,
    const float* __restrict__ z_depth,
    float* __restrict__ wgt, float* __restrict__ sxs, float* __restrict__ oxs,
    float* __restrict__ sys, float* __restrict__ oys, int* __restrict__ binst,
    int* __restrict__ rect, int* __restrict__ cidx, int* __restrict__ cnt,
    float* __restrict__ dec)
{
    __shared__ __align__(16) float sm[12928];   // 51,712 B

    const int bid = blockIdx.x;
    if (bid >= NINST) {   // 4 trailing blocks: box params
        box_params_dev(bid - NINST, z_where, z_present, z_depth,
                       wgt, sxs, oxs, sys, oys, binst, rect, cidx, cnt, sm);
        return;
    }
    const int loc = bid % 85;
    const int r2g = bid / 85;                // 0..3
    const int bp = r2g & 1, s = r2g >> 1;    // batch-pair, row-half
    const int inst0 = (2 * bp + 0) * 85 + loc;
    const int inst1 = (2 * bp + 1) * 85 + loc;

    const int tid = threadIdx.x;

    if (tid < 128) {   // s_x for both batches
        int q = tid >> 6, l = tid & 63;
        sm[q * SMB + l] = z_what[(q ? inst1 : inst0) * 64 + l];
    }
    if (tid >= 128 && tid < 320) {   // W5t[ft][c][k] stage (192 floats)
        int idx = tid - 128;
        int ft = idx / 48, rem = idx % 48;
        int cc = rem >> 4, k = rem & 15;
        sm[W5T + idx] = W5[(ft * 16 + k) * 3 + cc];
    }
    __syncthreads();

    // ---- L0: K=64 -> 256ch, row s, cols 0..1. 128 threads: (j0, co4).
    if (tid < 128) {
        const int co4 = tid & 63, j0 = tid >> 6;
        const int ft = 3 - (2 * s + j0);
        const float* wp = W0 + (size_t)ft * 64 * 256 + co4 * 4;
        float aA[4] = {0.f,0.f,0.f,0.f}, aB[4] = {0.f,0.f,0.f,0.f};
        #pragma unroll 4
        for (int kq = 0; kq < 16; ++kq) {
            float4 xA = *(const float4*)&sm[kq * 4];
            float4 xB = *(const float4*)&sm[SMB + kq * 4];
            #pragma unroll
            for (int kk = 0; kk < 4; ++kk) {
                float4 w4 = *(const float4*)&wp[(kq * 4 + kk) * 256];
                float xa = f4e(xA, kk), xb = f4e(xB, kk);
                aA[0] = fmaf(xa, w4.x, aA[0]); aA[1] = fmaf(xa, w4.y, aA[1]);
                aA[2] = fmaf(xa, w4.z, aA[2]); aA[3] = fmaf(xa, w4.w, aA[3]);
                aB[0] = fmaf(xb, w4.x, aB[0]); aB[1] = fmaf(xb, w4.y, aB[1]);
                aB[2] = fmaf(xb, w4.z, aB[2]); aB[3] = fmaf(xb, w4.w, aB[3]);
            }
        }
        float4 b4 = *(const float4*)&B0[co4 * 4];
        int o = 64 + j0 * 256 + co4 * 4;
        *(float4*)&sm[o] = make_float4(
            fmaxf(aA[0] + b4.x, 0.f), fmaxf(aA[1] + b4.y, 0.f),
            fmaxf(aA[2] + b4.z, 0.f), fmaxf(aA[3] + b4.w, 0.f));
        *(float4*)&sm[SMB + o] = make_float4(
            fmaxf(aB[0] + b4.x, 0.f), fmaxf(aB[1] + b4.y, 0.f),
            fmaxf(aB[2] + b4.z, 0.f), fmaxf(aB[3] + b4.w, 0.f));
    }
    __syncthreads();

    // ---- L1: K=256 -> 128ch, 2 rows x 4 cols. 256 threads: (tap, co4, j).
    if (tid < 256) {
        const int t = tid >> 6, co4 = (tid >> 1) & 31, j = tid & 1;
        const int di = t >> 1, dj = t & 1, ft = 3 - t;
        const float* wp = W1 + (size_t)ft * 256 * 128 + co4 * 4;
        float aA[4] = {0.f,0.f,0.f,0.f}, aB[4] = {0.f,0.f,0.f,0.f};
        #pragma unroll 4
        for (int kq = 0; kq < 64; ++kq) {
            float4 xA = *(const float4*)&sm[64 + j * 256 + kq * 4];
            float4 xB = *(const float4*)&sm[SMB + 64 + j * 256 + kq * 4];
            #pragma unroll
            for (int kk = 0; kk < 4; ++kk) {
                float4 w4 = *(const float4*)&wp[(kq * 4 + kk) * 128];
                float xa = f4e(xA, kk), xb = f4e(xB, kk);
                aA[0] = fmaf(xa, w4.x, aA[0]); aA[1] = fmaf(xa, w4.y, aA[1]);
                aA[2] = fmaf(xa, w4.z, aA[2]); aA[3] = fmaf(xa, w4.w, aA[3]);
                aB[0] = fmaf(xb, w4.x, aB[0]); aB[1] = fmaf(xb, w4.y, aB[1]);
                aB[2] = fmaf(xb, w4.z, aB[2]); aB[3] = fmaf(xb, w4.w, aB[3]);
            }
        }
        float4 b4 = *(const float4*)&B1[co4 * 4];
        int o = 576 + (di * 4 + 2 * j + dj) * 132 + co4 * 4;
        *(float4*)&sm[o] = make_float4(
            fmaxf(aA[0] + b4.x, 0.f), fmaxf(aA[1] + b4.y, 0.f),
            fmaxf(aA[2] + b4.z, 0.f), fmaxf(aA[3] + b4.w, 0.f));
        *(float4*)&sm[SMB + o] = make_float4(
            fmaxf(aB[0] + b4.x, 0.f), fmaxf(aB[1] + b4.y, 0.f),
            fmaxf(aB[2] + b4.z, 0.f), fmaxf(aB[3] + b4.w, 0.f));
    }
    __syncthreads();

    // ---- L2: K=128 -> 64ch, 4 rows x 8 cols. 512 threads: (orow, ocol, co4).
    {
        const int orow = tid >> 7, ocol = (tid >> 4) & 7, co4 = tid & 15;
        const int i = orow >> 1, di = orow & 1, j = ocol >> 1, dj = ocol & 1;
        const int ft = 3 - (2 * di + dj);
        const float* wp = W2 + (size_t)ft * 128 * 64 + co4 * 4;
        float aA[4] = {0.f,0.f,0.f,0.f}, aB[4] = {0.f,0.f,0.f,0.f};
        #pragma unroll 4
        for (int kq = 0; kq < 32; ++kq) {
            float4 xA = *(const float4*)&sm[576 + (i * 4 + j) * 132 + kq * 4];
            float4 xB = *(const float4*)&sm[SMB + 576 + (i * 4 + j) * 132 + kq * 4];
            #pragma unroll
            for (int kk = 0; kk < 4; ++kk) {
                float4 w4 = *(const float4*)&wp[(kq * 4 + kk) * 64];
                float xa = f4e(xA, kk), xb = f4e(xB, kk);
                aA[0] = fmaf(xa, w4.x, aA[0]); aA[1] = fmaf(xa, w4.y, aA[1]);
                aA[2] = fmaf(xa, w4.z, aA[2]); aA[3] = fmaf(xa, w4.w, aA[3]);
                aB[0] = fmaf(xb, w4.x, aB[0]); aB[1] = fmaf(xb, w4.y, aB[1]);
                aB[2] = fmaf(xb, w4.z, aB[2]); aB[3] = fmaf(xb, w4.w, aB[3]);
            }
        }
        float4 b4 = *(const float4*)&B2[co4 * 4];
        int o = 1632 + (orow * 8 + ocol) * 68 + co4 * 4;
        *(float4*)&sm[o] = make_float4(
            fmaxf(aA[0] + b4.x, 0.f), fmaxf(aA[1] + b4.y, 0.f),
            fmaxf(aA[2] + b4.z, 0.f), fmaxf(aA[3] + b4.w, 0.f));
        *(float4*)&sm[SMB + o] = make_float4(
            fmaxf(aB[0] + b4.x, 0.f), fmaxf(aB[1] + b4.y, 0.f),
            fmaxf(aB[2] + b4.z, 0.f), fmaxf(aB[3] + b4.w, 0.f));
    }
    __syncthreads();

    // ---- Chunks: per c, L3 (2 rows) -> L4 (4 rows) -> L5 (8 final rows).
    const float b50 = B5[0], b51 = B5[1], b52 = B5[2];

    for (int c = 0; c < 4; ++c) {
        {   // L3: K=64 -> 32ch, rows 2c..2c+1 (input aL2 row c), 16 cols.
            // 512 threads: (r, x3, co2) -- co-tile 2 via float2 weights.
            const int co2 = tid & 15, x3 = (tid >> 4) & 15, r = tid >> 8;
            const int j = x3 >> 1, dj = x3 & 1;
            const int ft = 3 - (2 * r + dj);
            const float* wp = W3 + (size_t)ft * 64 * 32 + co2 * 2;
            float aA0 = 0.f, aA1 = 0.f, aB0 = 0.f, aB1 = 0.f;
            #pragma unroll 4
            for (int kq = 0; kq < 16; ++kq) {
                float4 xA = *(const float4*)&sm[1632 + (c * 8 + j) * 68 + kq * 4];
                float4 xB = *(const float4*)&sm[SMB + 1632 + (c * 8 + j) * 68 + kq * 4];
                #pragma unroll
                for (int kk = 0; kk < 4; ++kk) {
                    float2 w2 = *(const float2*)&wp[(kq * 4 + kk) * 32];
                    float xa = f4e(xA, kk), xb = f4e(xB, kk);
                    aA0 = fmaf(xa, w2.x, aA0); aA1 = fmaf(xa, w2.y, aA1);
                    aB0 = fmaf(xb, w2.x, aB0); aB1 = fmaf(xb, w2.y, aB1);
                }
            }
            float2 b2 = *(const float2*)&B3[co2 * 2];
            int o = (r * 16 + x3) * 36 + co2 * 2;
            *(float2*)&sm[o] = make_float2(fmaxf(aA0 + b2.x, 0.f), fmaxf(aA1 + b2.y, 0.f));
            *(float2*)&sm[SMB + o] = make_float2(fmaxf(aB0 + b2.x, 0.f), fmaxf(aB1 + b2.y, 0.f));
        }
        __syncthreads();
        {   // L4: K=32 -> 16ch, chunk rows 0..3, 32 cols. (ocol, orow, co4).
            const int co4 = tid & 3, orow = (tid >> 2) & 3, ocol = tid >> 4;
            const int il = orow >> 1, di = orow & 1;
            const int j = ocol >> 1, dj = ocol & 1;
            const int ft = 3 - (2 * di + dj);
            const float* wp = W4 + (size_t)ft * 32 * 16 + co4 * 4;
            float aA[4] = {0.f,0.f,0.f,0.f}, aB[4] = {0.f,0.f,0.f,0.f};
            #pragma unroll
            for (int kq = 0; kq < 8; ++kq) {
                float4 xA = *(const float4*)&sm[(il * 16 + j) * 36 + kq * 4];
                float4 xB = *(const float4*)&sm[SMB + (il * 16 + j) * 36 + kq * 4];
                #pragma unroll
                for (int kk = 0; kk < 4; ++kk) {
                    float4 w4 = *(const float4*)&wp[(kq * 4 + kk) * 16];
                    float xa = f4e(xA, kk), xb = f4e(xB, kk);
                    aA[0] = fmaf(xa, w4.x, aA[0]); aA[1] = fmaf(xa, w4.y, aA[1]);
                    aA[2] = fmaf(xa, w4.z, aA[2]); aA[3] = fmaf(xa, w4.w, aA[3]);
                    aB[0] = fmaf(xb, w4.x, aB[0]); aB[1] = fmaf(xb, w4.y, aB[1]);
                    aB[2] = fmaf(xb, w4.z, aB[2]); aB[3] = fmaf(xb, w4.w, aB[3]);
                }
            }
            float4 b4 = *(const float4*)&B4[co4 * 4];
            int o = 3808 + (orow * 32 + ocol) * 20 + co4 * 4;
            *(float4*)&sm[o] = make_float4(
                fmaxf(aA[0] + b4.x, 0.f), fmaxf(aA[1] + b4.y, 0.f),
                fmaxf(aA[2] + b4.z, 0.f), fmaxf(aA[3] + b4.w, 0.f));
            *(float4*)&sm[SMB + o] = make_float4(
                fmaxf(aB[0] + b4.x, 0.f), fmaxf(aB[1] + b4.y, 0.f),
                fmaxf(aB[2] + b4.z, 0.f), fmaxf(aB[3] + b4.w, 0.f));
        }
        __syncthreads();
        {   // L5: K=16 -> 3ch sigmoid; rows 8c..8c+7 (global 32s+8c+g5), col x5.
            const int x5 = tid & 63, g5 = tid >> 6;
            const int lr = g5 >> 1, j = x5 >> 1;
            const int di5 = g5 & 1, dj5 = x5 & 1;
            const int ft5 = 3 - (2 * di5 + dj5);
            float aA0 = b50, aA1 = b51, aA2 = b52;
            float aB0 = b50, aB1 = b51, aB2 = b52;
            #pragma unroll
            for (int kq = 0; kq < 4; ++kq) {
                float4 xA = *(const float4*)&sm[3808 + (lr * 32 + j) * 20 + kq * 4];
                float4 xB = *(const float4*)&sm[SMB + 3808 + (lr * 32 + j) * 20 + kq * 4];
                float4 w0 = *(const float4*)&sm[W5T + ft5 * 48 +  0 + kq * 4];
                float4 w1 = *(const float4*)&sm[W5T + ft5 * 48 + 16 + kq * 4];
                float4 w2 = *(const float4*)&sm[W5T + ft5 * 48 + 32 + kq * 4];
                #pragma unroll
                for (int kk = 0; kk < 4; ++kk) {
                    float xa = f4e(xA, kk), xb = f4e(xB, kk);
                    float e0 = f4e(w0, kk), e1 = f4e(w1, kk), e2 = f4e(w2, kk);
                    aA0 = fmaf(xa, e0, aA0); aA1 = fmaf(xa, e1, aA1); aA2 = fmaf(xa, e2, aA2);
                    aB0 = fmaf(xb, e0, aB0); aB1 = fmaf(xb, e1, aB1); aB2 = fmaf(xb, e2, aB2);
                }
            }
            int row = 32 * s + 8 * c + g5;
            float* dpA = dec + (size_t)inst0 * 12288 + (size_t)(row * 64 + x5) * 3;
            float* dpB = dec + (size_t)inst1 * 12288 + (size_t)(row * 64 + x5) * 3;
            dpA[0] = 1.0f / (1.0f + expf(-aA0));
            dpA[1] = 1.0f / (1.0f + expf(-aA1));
            dpA[2] = 1.0f / (1.0f + expf(-aA2));
            dpB[0] = 1.0f / (1.0f + expf(-aB0));
            dpB[1] = 1.0f / (1.0f + expf(-aB1));
            dpB[2] = 1.0f / (1.0f + expf(-aB2));
        }
        __syncthreads();
    }
}

// Fused STN bilinear sample + weighted composite + in-block reduce.
// grid 512 = (b, 16x8 px tile); 1024 threads = 8 box-splits x 128 px.
__global__ __launch_bounds__(1024) void composite_k(
    const float* __restrict__ dec, const float* __restrict__ wgt,
    const float* __restrict__ sxs, const float* __restrict__ oxs,
    const float* __restrict__ sys, const float* __restrict__ oys,
    const int* __restrict__ binst, const int* __restrict__ rect,
    const int* __restrict__ cidx, const int* __restrict__ cnt,
    float* __restrict__ out)
{
    __shared__ float pls[8][128][3];   // 12 KB

    int b = blockIdx.x >> 7, tile = blockIdx.x & 127;      // 8 x-tiles x 16 y-tiles
    int tx0 = (tile & 7) << 4, ty0 = (tile >> 3) << 3;     // 16 wide x 8 tall
    int s = threadIdx.x >> 7, px = threadIdx.x & 127;
    int lx = px & 15, ly = px >> 4;                        // 16 x 8
    int w = tx0 + lx, h = ty0 + ly;

    int nb = cnt[b];
    int lo = (nb * s) >> 3, hi = (nb * (s + 1)) >> 3;

    float fw = (float)w, fh = (float)h;
    float a0 = 0.f, a1 = 0.f, a2 = 0.f;
    for (int q = lo; q < hi; ++q) {
        int n = cidx[b * NBOX + q];
        int rc = rect[b * NBOX + n];
        int wlo = rc & 255, whi = (rc >> 8) & 255;
        int hlo = (rc >> 16) & 255, hhi = (rc >> 24) & 255;
        if (whi < tx0 || wlo > tx0 + 15 || hhi < ty0 || hlo > ty0 + 7) continue;
        int g = b * NBOX + n;
        float wg = wgt[g];
        float pxx = fmaf(fw, sxs[g], oxs[g]);
        float pyy = fmaf(fh, sys[g], oys[g]);
        float x0 = floorf(pxx), y0 = floorf(pyy);
        if (x0 < -1.0f || x0 > 63.0f || y0 < -1.0f || y0 > 63.0f) continue;
        float wx = pxx - x0, wy = pyy - y0;
        int ix = (int)x0, iy = (int)y0;
        int x0c = max(ix, 0), x1c = min(ix + 1, 63);
        int y0c = max(iy, 0), y1c = min(iy + 1, 63);
        float m00 = (ix >= 0 && iy >= 0) ? 1.f : 0.f;
        float m01 = (ix + 1 <= 63 && iy >= 0) ? 1.f : 0.f;
        float m10 = (ix >= 0 && iy + 1 <= 63) ? 1.f : 0.f;
        float m11 = (ix + 1 <= 63 && iy + 1 <= 63) ? 1.f : 0.f;
        float w00 = (1.f - wy) * (1.f - wx) * m00;
        float w01 = (1.f - wy) * wx * m01;
        float w10 = wy * (1.f - wx) * m10;
        float w11 = wy * wx * m11;
        const float* img = dec + (size_t)binst[g] * 12288;   // (64,64,3) HWC
        int b00 = (y0c * 64 + x0c) * 3, b01 = (y0c * 64 + x1c) * 3;
        int b10 = (y1c * 64 + x0c) * 3, b11 = (y1c * 64 + x1c) * 3;
        a0 += wg * (w00 * img[b00]   + w01 * img[b01]   + w10 * img[b10]   + w11 * img[b11]);
        a1 += wg * (w00 * img[b00+1] + w01 * img[b01+1] + w10 * img[b10+1] + w11 * img[b11+1]);
        a2 += wg * (w00 * img[b00+2] + w01 * img[b01+2] + w10 * img[b10+2] + w11 * img[b11+2]);
    }
    pls[s][px][0] = a0; pls[s][px][1] = a1; pls[s][px][2] = a2;
    __syncthreads();

    if (threadIdx.x < 384) {
        int c = threadIdx.x >> 7, p2 = threadIdx.x & 127;
        float v = 0.f;
        #pragma unroll
        for (int t = 0; t < 8; ++t) v += pls[t][p2][c];
        int h2 = ty0 + (p2 >> 4), w2 = tx0 + (p2 & 15);
        out[((b * 3 + c) * 128 + h2) * 128 + w2] = v;
    }
}

extern "C" void kernel_launch(void* const* d_in, const int* in_sizes, int n_in,
                              void* d_out, int out_size, void* d_ws, size_t ws_size,
                              hipStream_t stream)
{
    const float* z_what    = (const float*)d_in[0];   // (4,85,64)
    const float* z_where   = (const float*)d_in[1];   // (4,380,4)
    const int*   z_present = (const int*)  d_in[2];   // (4,380,1)
    const float* z_depth   = (const float*)d_in[3];   // (4,85,1)

    // workspace: dec 16.71 MB | params ~55 KB
    char* ws = (char*)d_ws;
    float* dec = (float*)ws;                           // 340*12288 f32
    float* P   = (float*)(ws + 16711680);
    float* wgt = P,        *sxs = P + 1520, *oxs = P + 2 * 1520;
    float* sys = P + 3 * 1520, *oys = P + 4 * 1520;
    int* binst = (int*)(P + 5 * 1520);
    int* rect  = binst + 1520;
    int* cidx  = binst + 2 * 1520;
    int* cnt   = binst + 3 * 1520;

    decode_fused_k<<<dim3(NINST + 4), dim3(512), 0, stream>>>(
        z_what,
        (const float*)d_in[4],  (const float*)d_in[5],
        (const float*)d_in[6],  (const float*)d_in[7],
        (const float*)d_in[8],  (const float*)d_in[9],
        (const float*)d_in[10], (const float*)d_in[11],
        (const float*)d_in[12], (const float*)d_in[13],
        (const float*)d_in[14], (const float*)d_in[15],
        z_where, z_present, z_depth,
        wgt, sxs, oxs, sys, oys, binst, rect, cidx, cnt,
        dec);

    composite_k<<<dim3(512), dim3(1024), 0, stream>>>(
        dec, wgt, sxs, oxs, sys, oys, binst, rect, cidx, cnt, (float*)d_out);
}